// Round 1
// baseline (51.901 us; speedup 1.0000x reference)
//
#include <hip/hip_runtime.h>

#define DDIM 4096
#define BLOCK 256
#define WPB 4          // waves per block
#define GRID 2048

__global__ __launch_bounds__(BLOCK) void skinny_quad_kernel(
    const float* __restrict__ inp,
    const float* __restrict__ v,
    const float* __restrict__ w,
    const float* __restrict__ bptr,
    float* __restrict__ out,
    int B)
{
    __shared__ float sv[DDIM];
    __shared__ float sw[DDIM];

    const int tid = threadIdx.x;

    // Stage v and w into LDS once per block (coalesced float4).
    {
        const float4* v4 = reinterpret_cast<const float4*>(v);
        const float4* w4 = reinterpret_cast<const float4*>(w);
        float4* sv4 = reinterpret_cast<float4*>(sv);
        float4* sw4 = reinterpret_cast<float4*>(sw);
        #pragma unroll
        for (int i = 0; i < DDIM / 4 / BLOCK; ++i) {
            int idx = tid + i * BLOCK;
            sv4[idx] = v4[idx];
            sw4[idx] = w4[idx];
        }
    }
    __syncthreads();

    const float bias = bptr[0];

    const int wave  = tid >> 6;
    const int lane  = tid & 63;
    const int gwave = blockIdx.x * WPB + wave;
    const int nwav  = GRID * WPB;

    const float4* sv4 = reinterpret_cast<const float4*>(sv);
    const float4* sw4 = reinterpret_cast<const float4*>(sw);

    for (int row = gwave; row < B; row += nwav) {
        const float4* x4 = reinterpret_cast<const float4*>(inp + (size_t)row * DDIM);
        float q = 0.0f;
        float l = 0.0f;
        #pragma unroll
        for (int k = 0; k < DDIM / 4 / 64; ++k) {
            const int idx = lane + k * 64;
            const float4 x  = x4[idx];
            const float4 vv = sv4[idx];
            const float4 ww = sw4[idx];
            q = fmaf(x.x, vv.x, q);
            q = fmaf(x.y, vv.y, q);
            q = fmaf(x.z, vv.z, q);
            q = fmaf(x.w, vv.w, q);
            l = fmaf(x.x, ww.x, l);
            l = fmaf(x.y, ww.y, l);
            l = fmaf(x.z, ww.z, l);
            l = fmaf(x.w, ww.w, l);
        }
        // 64-lane butterfly reduction
        #pragma unroll
        for (int off = 32; off > 0; off >>= 1) {
            q += __shfl_down(q, off);
            l += __shfl_down(l, off);
        }
        if (lane == 0) {
            out[row] = fmaf(-q, q, l + bias);
        }
    }
}

extern "C" void kernel_launch(void* const* d_in, const int* in_sizes, int n_in,
                              void* d_out, int out_size, void* d_ws, size_t ws_size,
                              hipStream_t stream) {
    const float* inp  = (const float*)d_in[0];   // (B, D) fp32
    const float* qp   = (const float*)d_in[1];   // (D, 1) fp32
    const float* lw   = (const float*)d_in[2];   // (1, D) fp32
    const float* lb   = (const float*)d_in[3];   // (1,)  fp32
    float* out        = (float*)d_out;           // (B,)  fp32

    const int B = in_sizes[0] / DDIM;

    skinny_quad_kernel<<<GRID, BLOCK, 0, stream>>>(inp, qp, lw, lb, out, B);
}

// Round 2
// 44.735 us; speedup vs baseline: 1.1602x; 1.1602x over previous
//
#include <hip/hip_runtime.h>

#define DDIM 4096
#define BLOCK 256
#define WPB 4          // waves per block
#define GRID 2048      // 8192 waves * 2 rows/wave = 16384 rows exactly

__global__ __launch_bounds__(BLOCK) void skinny_quad_kernel(
    const float* __restrict__ inp,
    const float* __restrict__ v,
    const float* __restrict__ w,
    const float* __restrict__ bptr,
    float* __restrict__ out,
    int B)
{
    __shared__ float sv[DDIM];
    __shared__ float sw[DDIM];

    const int tid = threadIdx.x;

    // Stage v and w into LDS once per block (coalesced float4).
    {
        const float4* v4 = reinterpret_cast<const float4*>(v);
        const float4* w4 = reinterpret_cast<const float4*>(w);
        float4* sv4 = reinterpret_cast<float4*>(sv);
        float4* sw4 = reinterpret_cast<float4*>(sw);
        #pragma unroll
        for (int i = 0; i < DDIM / 4 / BLOCK; ++i) {
            int idx = tid + i * BLOCK;
            sv4[idx] = v4[idx];
            sw4[idx] = w4[idx];
        }
    }
    __syncthreads();

    const float bias = bptr[0];

    const int wave  = tid >> 6;
    const int lane  = tid & 63;
    const int gwave = blockIdx.x * WPB + wave;

    const int r0 = 2 * gwave;
    const int r1 = r0 + 1;
    if (r0 >= B) return;

    const float4* sv4 = reinterpret_cast<const float4*>(sv);
    const float4* sw4 = reinterpret_cast<const float4*>(sw);

    const float4* x04 = reinterpret_cast<const float4*>(inp + (size_t)r0 * DDIM);
    const float4* x14 = reinterpret_cast<const float4*>(inp + (size_t)r1 * DDIM);

    float q0 = 0.0f, l0 = 0.0f;
    float q1 = 0.0f, l1 = 0.0f;

    #pragma unroll
    for (int k = 0; k < DDIM / 4 / 64; ++k) {
        const int idx = lane + k * 64;
        const float4 a  = x04[idx];
        const float4 c  = x14[idx];
        const float4 vv = sv4[idx];
        const float4 ww = sw4[idx];
        q0 = fmaf(a.x, vv.x, q0);
        q0 = fmaf(a.y, vv.y, q0);
        q0 = fmaf(a.z, vv.z, q0);
        q0 = fmaf(a.w, vv.w, q0);
        l0 = fmaf(a.x, ww.x, l0);
        l0 = fmaf(a.y, ww.y, l0);
        l0 = fmaf(a.z, ww.z, l0);
        l0 = fmaf(a.w, ww.w, l0);
        q1 = fmaf(c.x, vv.x, q1);
        q1 = fmaf(c.y, vv.y, q1);
        q1 = fmaf(c.z, vv.z, q1);
        q1 = fmaf(c.w, vv.w, q1);
        l1 = fmaf(c.x, ww.x, l1);
        l1 = fmaf(c.y, ww.y, l1);
        l1 = fmaf(c.z, ww.z, l1);
        l1 = fmaf(c.w, ww.w, l1);
    }

    // 64-lane butterfly reduction of all four accumulators
    #pragma unroll
    for (int off = 32; off > 0; off >>= 1) {
        q0 += __shfl_xor(q0, off);
        l0 += __shfl_xor(l0, off);
        q1 += __shfl_xor(q1, off);
        l1 += __shfl_xor(l1, off);
    }

    if (lane == 0) {
        out[r0] = fmaf(-q0, q0, l0 + bias);
        if (r1 < B) out[r1] = fmaf(-q1, q1, l1 + bias);
    }
}

extern "C" void kernel_launch(void* const* d_in, const int* in_sizes, int n_in,
                              void* d_out, int out_size, void* d_ws, size_t ws_size,
                              hipStream_t stream) {
    const float* inp  = (const float*)d_in[0];   // (B, D) fp32
    const float* qp   = (const float*)d_in[1];   // (D, 1) fp32
    const float* lw   = (const float*)d_in[2];   // (1, D) fp32
    const float* lb   = (const float*)d_in[3];   // (1,)  fp32
    float* out        = (float*)d_out;           // (B,)  fp32

    const int B = in_sizes[0] / DDIM;

    skinny_quad_kernel<<<GRID, BLOCK, 0, stream>>>(inp, qp, lw, lb, out, B);
}